// Round 11
// baseline (670.121 us; speedup 1.0000x reference)
//
#include <hip/hip_runtime.h>
#include <hip/hip_bf16.h>
#include <stdint.h>

#define G_MAX 64
#define F_DIM 512
#define H_DIM 512

typedef __attribute__((ext_vector_type(8))) short short8;
typedef __attribute__((ext_vector_type(4))) float f32x4;

__device__ __forceinline__ unsigned short cvt_bf16(float x) {
    union { float f; unsigned u; } c; c.f = x;
    return (unsigned short)((c.u + 0x7FFFu + ((c.u >> 16) & 1u)) >> 16);
}

// ---------------- init: zero outputs + accumulators ----------------
__global__ void init_kernel(float* __restrict__ out, float* __restrict__ stressacc,
                            float* __restrict__ forces, int N) {
    int i = blockIdx.x * 256 + threadIdx.x;
    int total = N * 3;
    for (int k = i; k < total; k += gridDim.x * 256) forces[k] = 0.f;
    if (i < 2 * G_MAX + G_MAX * 9) out[i] = 0.f;
    if (i < G_MAX * 9) stressacc[i] = 0.f;
}

// ---------------- transpose w1 [F][H] f32 -> w1T [H][F] bf16 ----------------
__global__ void transpose_w1_kernel(const float* __restrict__ w1, unsigned short* __restrict__ w1T) {
    int idx = blockIdx.x * 256 + threadIdx.x;   // 0 .. 512*512-1
    int h = idx >> 9;
    int f = idx & 511;
    w1T[idx] = cvt_bf16(w1[f * H_DIM + h]);
}

// ---------------- u = w_pos @ w1  -> [3][H] f32 ----------------
__global__ void compute_u_kernel(const float* __restrict__ w_pos, const float* __restrict__ w1,
                                 float* __restrict__ u) {
    int h = threadIdx.x;   // 512 threads, 1 block
    float a0 = 0.f, a1 = 0.f, a2 = 0.f;
    for (int f = 0; f < F_DIM; ++f) {
        float wv = w1[f * H_DIM + h];
        a0 += w_pos[f] * wv;
        a1 += w_pos[F_DIM + f] * wv;
        a2 += w_pos[2 * F_DIM + f] * wv;
    }
    u[h] = a0; u[H_DIM + h] = a1; u[2 * H_DIM + h] = a2;
}

// ---------------- fused node GEMM: z, silu, energy, forces ----------------
// grid: ceil(N/64) blocks x 512 threads (8 waves). Wave w owns cols [w*64, w*64+64).
__global__ __launch_bounds__(512)
void fused_node_kernel(const float* __restrict__ node_feats,
                       const float* __restrict__ pos,
                       const int*   __restrict__ batch,
                       const unsigned short* __restrict__ w1T,  // [H][F] bf16
                       const float* __restrict__ u,             // [3][H]
                       const float* __restrict__ b1,            // [H]
                       const float* __restrict__ w2,            // [H]
                       const float* __restrict__ b2,            // [1]
                       float* __restrict__ forces,              // [N][3]
                       float* __restrict__ energy,              // [G]
                       int N) {
    __shared__ __align__(16) unsigned short As[2][64 * 64];
    __shared__ float posl[64 * 3];
    __shared__ float red[64 * 4];
    __shared__ float e_graph[G_MAX];

    const int tid  = threadIdx.x;
    const int lane = tid & 63;
    const int w    = tid >> 6;
    const int blockRow = blockIdx.x * 64;

    // prologue: pos tile, zero reductions
    if (tid < 192) {
        int idx = blockRow * 3 + tid;
        posl[tid] = (idx < N * 3) ? pos[idx] : 0.f;
    }
    if (tid < G_MAX) e_graph[tid] = 0.f;
    if (tid >= 256 && tid < 512) red[tid - 256] = 0.f;

    // A staging geometry: thread t -> row t>>3, k-chunk (t&7)*8  (8 f32 each)
    const int srow = tid >> 3;
    const int scol = (tid & 7) * 8;
    int grow_s = blockRow + srow; if (grow_s >= N) grow_s = N - 1;
    const float* aptr = node_feats + (size_t)grow_s * F_DIM + scol;
    const int sw_idx = srow * 64 + (scol ^ ((srow & 7) << 3));  // swizzled ushort index

    // stage kt=0
    {
        const float4* p = (const float4*)(aptr);
        float4 x0 = p[0], x1 = p[1];
        short8 v;
        v[0] = (short)cvt_bf16(x0.x); v[1] = (short)cvt_bf16(x0.y);
        v[2] = (short)cvt_bf16(x0.z); v[3] = (short)cvt_bf16(x0.w);
        v[4] = (short)cvt_bf16(x1.x); v[5] = (short)cvt_bf16(x1.y);
        v[6] = (short)cvt_bf16(x1.z); v[7] = (short)cvt_bf16(x1.w);
        *(short8*)&As[0][sw_idx] = v;
    }
    __syncthreads();

    f32x4 acc[4][4];
    #pragma unroll
    for (int rf = 0; rf < 4; ++rf)
        #pragma unroll
        for (int cf = 0; cf < 4; ++cf)
            acc[rf][cf] = (f32x4){0.f, 0.f, 0.f, 0.f};

    const int l15 = lane & 15;
    const int lhi = lane >> 4;   // 0..3

    int cur = 0;
    #pragma unroll
    for (int kt = 0; kt < 8; ++kt) {
        // prefetch next A tile (global f32)
        float4 x0, x1;
        if (kt < 7) {
            const float4* p = (const float4*)(aptr + (kt + 1) * 64);
            x0 = p[0]; x1 = p[1];
        }
        // B fragments from w1T (bf16, L2-hot): col = w*64+cf*16+l15, k = kt*64+ks*32+lhi*8
        short8 bfr[2][4];
        #pragma unroll
        for (int ks = 0; ks < 2; ++ks)
            #pragma unroll
            for (int cf = 0; cf < 4; ++cf) {
                int col = w * 64 + cf * 16 + l15;
                int k   = kt * 64 + ks * 32 + lhi * 8;
                bfr[ks][cf] = *(const short8*)(w1T + (size_t)col * F_DIM + k);
            }
        // A fragments from LDS: row = rf*16+l15, k = ks*32+lhi*8
        short8 afr[2][4];
        #pragma unroll
        for (int ks = 0; ks < 2; ++ks)
            #pragma unroll
            for (int rf = 0; rf < 4; ++rf) {
                int r = rf * 16 + l15;
                int k = ks * 32 + lhi * 8;
                int idx = r * 64 + (k ^ ((r & 7) << 3));
                afr[ks][rf] = *(const short8*)&As[cur][idx];
            }
        // MFMA
        #pragma unroll
        for (int ks = 0; ks < 2; ++ks)
            #pragma unroll
            for (int rf = 0; rf < 4; ++rf)
                #pragma unroll
                for (int cf = 0; cf < 4; ++cf)
                    acc[rf][cf] = __builtin_amdgcn_mfma_f32_16x16x32_bf16(
                        afr[ks][rf], bfr[ks][cf], acc[rf][cf], 0, 0, 0);
        // write next tile
        if (kt < 7) {
            short8 v;
            v[0] = (short)cvt_bf16(x0.x); v[1] = (short)cvt_bf16(x0.y);
            v[2] = (short)cvt_bf16(x0.z); v[3] = (short)cvt_bf16(x0.w);
            v[4] = (short)cvt_bf16(x1.x); v[5] = (short)cvt_bf16(x1.y);
            v[6] = (short)cvt_bf16(x1.z); v[7] = (short)cvt_bf16(x1.w);
            *(short8*)&As[cur ^ 1][sw_idx] = v;
        }
        __syncthreads();
        cur ^= 1;
    }

    // ---- epilogue: z -> silu/silu' -> per-row energy + forces ----
    const int c0 = w * 64 + l15;
    float uc0[4], uc1[4], uc2[4], b1c[4], w2c[4];
    #pragma unroll
    for (int cf = 0; cf < 4; ++cf) {
        int col = c0 + cf * 16;
        uc0[cf] = u[col];
        uc1[cf] = u[H_DIM + col];
        uc2[cf] = u[2 * H_DIM + col];
        b1c[cf] = b1[col];
        w2c[cf] = w2[col];
    }

    #pragma unroll
    for (int rf = 0; rf < 4; ++rf) {
        #pragma unroll
        for (int j = 0; j < 4; ++j) {
            int rl = rf * 16 + (lhi << 2) + j;
            float px = posl[rl * 3 + 0], py = posl[rl * 3 + 1], pz = posl[rl * 3 + 2];
            float pe = 0.f, f0 = 0.f, f1 = 0.f, f2 = 0.f;
            #pragma unroll
            for (int cf = 0; cf < 4; ++cf) {
                float z = acc[rf][cf][j] + px * uc0[cf] + py * uc1[cf] + pz * uc2[cf] + b1c[cf];
                float sg = 1.f / (1.f + __expf(-z));
                float silu = z * sg;
                float dsilu = sg * (1.f + z * (1.f - sg));
                float t = dsilu * w2c[cf];
                pe += silu * w2c[cf];
                f0 += t * uc0[cf];
                f1 += t * uc1[cf];
                f2 += t * uc2[cf];
            }
            // reduce over the 16 lanes holding this row's 64 wave-columns
            #pragma unroll
            for (int m = 1; m < 16; m <<= 1) {
                pe += __shfl_xor(pe, m, 64);
                f0 += __shfl_xor(f0, m, 64);
                f1 += __shfl_xor(f1, m, 64);
                f2 += __shfl_xor(f2, m, 64);
            }
            if (l15 == 0) {
                atomicAdd(&red[rl * 4 + 0], pe);
                atomicAdd(&red[rl * 4 + 1], f0);
                atomicAdd(&red[rl * 4 + 2], f1);
                atomicAdd(&red[rl * 4 + 3], f2);
            }
        }
    }
    __syncthreads();

    if (tid < 64) {
        int grow = blockRow + tid;
        if (grow < N) {
            float pe = red[tid * 4 + 0] + b2[0];
            forces[grow * 3 + 0] = red[tid * 4 + 1];
            forces[grow * 3 + 1] = red[tid * 4 + 2];
            forces[grow * 3 + 2] = red[tid * 4 + 3];
            atomicAdd(&e_graph[batch[grow]], pe);
        }
    }
    __syncthreads();
    if (tid < G_MAX) {
        float v = e_graph[tid];
        if (v != 0.f) atomicAdd(&energy[tid], v);
    }
}

// ---------------- num_atoms ----------------
__global__ void count_kernel(const int* __restrict__ batch, float* __restrict__ natoms, int N) {
    __shared__ float c[G_MAX];
    if (threadIdx.x < G_MAX) c[threadIdx.x] = 0.f;
    __syncthreads();
    int stride = gridDim.x * 256;
    for (int i = blockIdx.x * 256 + threadIdx.x; i < N; i += stride)
        atomicAdd(&c[batch[i]], 1.f);
    __syncthreads();
    if (threadIdx.x < G_MAX) {
        float v = c[threadIdx.x];
        if (v != 0.f) atomicAdd(&natoms[threadIdx.x], v);
    }
}

// ---------------- per-edge virial accumulation ----------------
__global__ __launch_bounds__(256)
void edge_stress_kernel(const int* __restrict__ ei, const float* __restrict__ ea,
                        const int* __restrict__ batch, const float* __restrict__ forces,
                        float* __restrict__ stressacc, int E) {
    __shared__ float s[G_MAX * 9];
    for (int i = threadIdx.x; i < G_MAX * 9; i += 256) s[i] = 0.f;
    __syncthreads();
    int stride = gridDim.x * 256;
    for (int e = blockIdx.x * 256 + threadIdx.x; e < E; e += stride) {
        int r = ei[e];
        int c = ei[E + e];
        int g = batch[r];
        const float* fp = forces + (size_t)c * 3;
        float f0 = fp[0], f1 = fp[1], f2 = fp[2];
        const float* ap = ea + (size_t)e * 3;
        float a0 = ap[0], a1 = ap[1], a2 = ap[2];
        float* sp = s + g * 9;
        atomicAdd(sp + 0, a0 * f0); atomicAdd(sp + 1, a0 * f1); atomicAdd(sp + 2, a0 * f2);
        atomicAdd(sp + 3, a1 * f0); atomicAdd(sp + 4, a1 * f1); atomicAdd(sp + 5, a1 * f2);
        atomicAdd(sp + 6, a2 * f0); atomicAdd(sp + 7, a2 * f1); atomicAdd(sp + 8, a2 * f2);
    }
    __syncthreads();
    for (int i = threadIdx.x; i < G_MAX * 9; i += 256)
        atomicAdd(&stressacc[i], s[i]);
}

// ---------------- finalize: stress / |det(cell)| ----------------
__global__ void finalize_kernel(const float* __restrict__ cell, const float* __restrict__ stressacc,
                                float* __restrict__ stress_out, int Gn) {
    int j = blockIdx.x * 256 + threadIdx.x;
    if (j < Gn * 9) {
        int g = j / 9;
        const float* c = cell + g * 9;
        float det = c[0] * (c[4] * c[8] - c[5] * c[7])
                  - c[1] * (c[3] * c[8] - c[5] * c[6])
                  + c[2] * (c[3] * c[7] - c[4] * c[6]);
        float vol = fmaxf(fabsf(det), 1e-10f);
        stress_out[j] = stressacc[j] / vol;
    }
}

extern "C" void kernel_launch(void* const* d_in, const int* in_sizes, int n_in,
                              void* d_out, int out_size, void* d_ws, size_t ws_size,
                              hipStream_t stream) {
    const float* node_feats = (const float*)d_in[0];
    const float* pos        = (const float*)d_in[1];
    const float* edge_attr  = (const float*)d_in[2];
    const float* cell       = (const float*)d_in[3];
    const int*   batch      = (const int*)d_in[4];
    const int*   edge_index = (const int*)d_in[5];
    const float* w_pos      = (const float*)d_in[6];
    const float* w1         = (const float*)d_in[7];
    const float* b1         = (const float*)d_in[8];
    const float* w2         = (const float*)d_in[9];
    const float* b2         = (const float*)d_in[10];

    int N  = in_sizes[4];
    int E  = in_sizes[5] / 2;
    int Gn = in_sizes[3] / 9;   // 64

    float* out        = (float*)d_out;
    float* energy     = out;
    float* natoms     = out + Gn;
    float* stress_out = out + 2 * Gn;

    char* ws = (char*)d_ws;
    unsigned short* w1T = (unsigned short*)ws;                       // 512KB
    float* u      = (float*)(ws + (size_t)H_DIM * F_DIM * 2);        // 6KB
    float* forces = (float*)(ws + (size_t)H_DIM * F_DIM * 2 + 3 * H_DIM * 4);
    size_t foff = (size_t)H_DIM * F_DIM * 2 + 3 * H_DIM * 4;
    size_t fbytes = (((size_t)N * 12) + 255) / 256 * 256;
    float* stressacc = (float*)(ws + foff + fbytes);

    init_kernel<<<(3 * N + 255) / 256, 256, 0, stream>>>(out, stressacc, forces, N);
    transpose_w1_kernel<<<(F_DIM * H_DIM) / 256, 256, 0, stream>>>(w1, w1T);
    compute_u_kernel<<<1, H_DIM, 0, stream>>>(w_pos, w1, u);
    fused_node_kernel<<<(N + 63) / 64, 512, 0, stream>>>(node_feats, pos, batch, w1T, u, b1, w2, b2,
                                                         forces, energy, N);
    count_kernel<<<256, 256, 0, stream>>>(batch, natoms, N);
    edge_stress_kernel<<<1024, 256, 0, stream>>>(edge_index, edge_attr, batch, forces, stressacc, E);
    finalize_kernel<<<(Gn * 9 + 255) / 256, 256, 0, stream>>>(cell, stressacc, stress_out, Gn);
}